// Round 3
// baseline (1162.603 us; speedup 1.0000x reference)
//
#include <hip/hip_runtime.h>
#include <hip/hip_fp16.h>
#include <cstddef>
#include <cstdint>

#define N_PTS 16384
#define K_PTS 1024
#define D_DIM 512
#define EPS_F 0.1f
#define ITERS 20
#define MU_F (1.0f/16384.0f)
#define NU_F (1.0f/1024.0f)
#define NCOPY 8
#define SINK_BLOCKS 256

typedef float f32x4 __attribute__((ext_vector_type(4)));
typedef short s16x8 __attribute__((ext_vector_type(8)));

__device__ __forceinline__ float wave_reduce_sum(float s) {
#pragma unroll
  for (int off = 32; off > 0; off >>= 1) s += __shfl_xor(s, off, 64);
  return s;
}
__device__ __forceinline__ float wave_reduce_max(float s) {
#pragma unroll
  for (int off = 32; off > 0; off >>= 1) s = fmaxf(s, __shfl_xor(s, off, 64));
  return s;
}
__device__ __forceinline__ unsigned short f2bf(float f) {  // RNE, finite inputs
  unsigned int b = __float_as_uint(f);
  b += 0x7fffu + ((b >> 16) & 1u);
  return (unsigned short)(b >> 16);
}
__device__ __forceinline__ float bf2f(unsigned short h) {
  return __uint_as_float(((unsigned int)h) << 16);
}
__device__ __forceinline__ void unpack2(unsigned int w, float& f0, float& f1) {
  f0 = __uint_as_float(w << 16);
  f1 = __uint_as_float(w & 0xffff0000u);
}

// ---------------------------------------------------------------- init
__global__ __launch_bounds__(256) void init_kernel(float* __restrict__ accum,
                                                   unsigned int* __restrict__ cnt,
                                                   unsigned int* __restrict__ maxbits,
                                                   float* __restrict__ loss) {
  int i = blockIdx.x * 256 + threadIdx.x;
  const int total = (ITERS + 1) * NCOPY * K_PTS;
  if (i < total) accum[i] = 0.0f;
  if (blockIdx.x == 0) {
    if (threadIdx.x < 32) cnt[threadIdx.x] = 0u;
    if (threadIdx.x == 0) { *maxbits = 0u; *loss = 0.0f; }
  }
}

// ---------------------------------------------------------------- row norms
__global__ __launch_bounds__(256) void rownorm_kernel(const float* __restrict__ A,
                                                      float* __restrict__ out, int rows) {
  int wave = (blockIdx.x * 256 + threadIdx.x) >> 6;
  int lane = threadIdx.x & 63;
  if (wave >= rows) return;
  const float4* rp = (const float4*)(A + (size_t)wave * D_DIM);
  float4 a = rp[lane];
  float4 b = rp[lane + 64];
  float s = a.x*a.x + a.y*a.y + a.z*a.z + a.w*a.w
          + b.x*b.x + b.y*b.y + b.z*b.z + b.w*b.w;
  s = wave_reduce_sum(s);
  if (lane == 0) out[wave] = s;
}

// ---------------------------------------------------------------- split-bf16 MFMA GEMM
// C(fp16, to d_out scratch) = dx + pn - 2*x@p^T, track global max (on fp32 values).
#define LDSW 40  // 32 bf16 + 8 pad
__global__ __launch_bounds__(256) void gemm_kernel(const float* __restrict__ X,
                                                   const float* __restrict__ P,
                                                   const float* __restrict__ dx,
                                                   const float* __restrict__ pn,
                                                   __half* __restrict__ Ch,
                                                   unsigned int* __restrict__ maxbits) {
  __shared__ __align__(16) unsigned short Ah[128 * LDSW];
  __shared__ __align__(16) unsigned short Al[128 * LDSW];
  __shared__ __align__(16) unsigned short Bh[128 * LDSW];
  __shared__ __align__(16) unsigned short Bl[128 * LDSW];

  const int tid = threadIdx.x;
  const int lane = tid & 63, wv = tid >> 6;
  const int wm = wv >> 1, wn = wv & 1;
  const int m0 = blockIdx.y * 128, k0 = blockIdx.x * 128;
  const int lrow = tid >> 1, lhalf = tid & 1;

  const float* xrow = X + (size_t)(m0 + lrow) * D_DIM + lhalf * 16;
  const float* prow = P + (size_t)(k0 + lrow) * D_DIM + lhalf * 16;
  const int ldsoff = lrow * LDSW + lhalf * 16;

  f32x4 acc[4][4] = {};

  for (int d0 = 0; d0 < D_DIM; d0 += 32) {
    float av[16], bv[16];
    {
      const float4* xp = (const float4*)(xrow + d0);
      const float4* pp = (const float4*)(prow + d0);
#pragma unroll
      for (int q = 0; q < 4; q++) {
        float4 a = xp[q], b = pp[q];
        av[q*4+0]=a.x; av[q*4+1]=a.y; av[q*4+2]=a.z; av[q*4+3]=a.w;
        bv[q*4+0]=b.x; bv[q*4+1]=b.y; bv[q*4+2]=b.z; bv[q*4+3]=b.w;
      }
    }
    unsigned int ahu[8], alu[8], bhu[8], blu[8];
#pragma unroll
    for (int j = 0; j < 8; j++) {
      float f0 = av[2*j], f1 = av[2*j+1];
      unsigned short h0 = f2bf(f0), h1 = f2bf(f1);
      unsigned short l0 = f2bf(f0 - bf2f(h0)), l1 = f2bf(f1 - bf2f(h1));
      ahu[j] = (unsigned int)h0 | ((unsigned int)h1 << 16);
      alu[j] = (unsigned int)l0 | ((unsigned int)l1 << 16);
      f0 = bv[2*j]; f1 = bv[2*j+1];
      h0 = f2bf(f0); h1 = f2bf(f1);
      l0 = f2bf(f0 - bf2f(h0)); l1 = f2bf(f1 - bf2f(h1));
      bhu[j] = (unsigned int)h0 | ((unsigned int)h1 << 16);
      blu[j] = (unsigned int)l0 | ((unsigned int)l1 << 16);
    }
    __syncthreads();
    *(uint4*)&Ah[ldsoff]     = make_uint4(ahu[0], ahu[1], ahu[2], ahu[3]);
    *(uint4*)&Ah[ldsoff + 8] = make_uint4(ahu[4], ahu[5], ahu[6], ahu[7]);
    *(uint4*)&Al[ldsoff]     = make_uint4(alu[0], alu[1], alu[2], alu[3]);
    *(uint4*)&Al[ldsoff + 8] = make_uint4(alu[4], alu[5], alu[6], alu[7]);
    *(uint4*)&Bh[ldsoff]     = make_uint4(bhu[0], bhu[1], bhu[2], bhu[3]);
    *(uint4*)&Bh[ldsoff + 8] = make_uint4(bhu[4], bhu[5], bhu[6], bhu[7]);
    *(uint4*)&Bl[ldsoff]     = make_uint4(blu[0], blu[1], blu[2], blu[3]);
    *(uint4*)&Bl[ldsoff + 8] = make_uint4(blu[4], blu[5], blu[6], blu[7]);
    __syncthreads();

    const int offA = (wm * 64 + (lane & 15)) * LDSW + (lane >> 4) * 8;
    const int offB = (wn * 64 + (lane & 15)) * LDSW + (lane >> 4) * 8;
    s16x8 ah[4], al[4], bh[4], bl[4];
#pragma unroll
    for (int i = 0; i < 4; i++) {
      ah[i] = *(const s16x8*)&Ah[offA + i * 16 * LDSW];
      al[i] = *(const s16x8*)&Al[offA + i * 16 * LDSW];
      bh[i] = *(const s16x8*)&Bh[offB + i * 16 * LDSW];
      bl[i] = *(const s16x8*)&Bl[offB + i * 16 * LDSW];
    }
#pragma unroll
    for (int mi = 0; mi < 4; mi++)
#pragma unroll
      for (int ni = 0; ni < 4; ni++) {
        acc[mi][ni] = __builtin_amdgcn_mfma_f32_16x16x32_bf16(ah[mi], bh[ni], acc[mi][ni], 0, 0, 0);
        acc[mi][ni] = __builtin_amdgcn_mfma_f32_16x16x32_bf16(ah[mi], bl[ni], acc[mi][ni], 0, 0, 0);
        acc[mi][ni] = __builtin_amdgcn_mfma_f32_16x16x32_bf16(al[mi], bh[ni], acc[mi][ni], 0, 0, 0);
      }
  }

  // epilogue: C/D layout col=lane&15, row=(lane>>4)*4+reg
  float lmax = -3.4e38f;
#pragma unroll
  for (int mi = 0; mi < 4; mi++) {
    int rb = m0 + wm * 64 + mi * 16 + (lane >> 4) * 4;
    float dxv[4];
#pragma unroll
    for (int r = 0; r < 4; r++) dxv[r] = dx[rb + r];
#pragma unroll
    for (int ni = 0; ni < 4; ni++) {
      int c = k0 + wn * 64 + ni * 16 + (lane & 15);
      float pnc = pn[c];
#pragma unroll
      for (int r = 0; r < 4; r++) {
        float val = dxv[r] + pnc - 2.0f * acc[mi][ni][r];
        Ch[(size_t)(rb + r) * K_PTS + c] = __float2half(val);
        lmax = fmaxf(lmax, val);
      }
    }
  }
  lmax = wave_reduce_max(lmax);
  __shared__ float wmax[4];
  if (lane == 0) wmax[wv] = lmax;
  __syncthreads();
  if (tid == 0) {
    float m = fmaxf(fmaxf(wmax[0], wmax[1]), fmaxf(wmax[2], wmax[3]));
    atomicMax((int*)maxbits, __float_as_int(m));  // global max is positive
  }
}

// ---------------------------------------------------------------- K_eps = bf16(exp(C * factor)), C fp16
__global__ __launch_bounds__(256) void expk_kernel(const __half* __restrict__ Ch,
                                                   unsigned short* __restrict__ Kb,
                                                   const unsigned int* __restrict__ maxbits) {
  float cmax = __int_as_float((int)*maxbits);
  float factor = -1.0f / ((cmax + 1e-8f) * EPS_F);
  size_t g = (size_t)blockIdx.x * 256 + threadIdx.x;  // 8 halves per thread
  uint4 w = ((const uint4*)Ch)[g];
  const __half2* hp = (const __half2*)&w;
  float k[8];
#pragma unroll
  for (int q = 0; q < 4; q++) {
    float2 c2 = __half22float2(hp[q]);
    k[2*q+0] = __expf(c2.x * factor);
    k[2*q+1] = __expf(c2.y * factor);
  }
  unsigned int u0 = (unsigned int)f2bf(k[0]) | ((unsigned int)f2bf(k[1]) << 16);
  unsigned int u1 = (unsigned int)f2bf(k[2]) | ((unsigned int)f2bf(k[3]) << 16);
  unsigned int u2 = (unsigned int)f2bf(k[4]) | ((unsigned int)f2bf(k[5]) << 16);
  unsigned int u3 = (unsigned int)f2bf(k[6]) | ((unsigned int)f2bf(k[7]) << 16);
  ((uint4*)Kb)[g] = make_uint4(u0, u1, u2, u3);
}

// ---------------------------------------------------------------- persistent Sinkhorn: all 20 iterations
// 256 blocks x 512 threads (1 block/CU). Block b owns rows [b*64, b*64+64) -> L2-resident re-reads.
// Per iter: u_i = MU/(K[i,:]·v + 1e-8); colsum += K^T·u (8-copy atomics); grid barrier; v = NU/(colsum+1e-8).
__global__ __launch_bounds__(512, 2) void sinkhorn_kernel(
    const unsigned short* __restrict__ Kb,
    float* __restrict__ accum,          // (ITERS+1) stages x NCOPY x K_PTS
    unsigned int* __restrict__ cnt,     // ITERS arrival counters
    float* __restrict__ u_out) {
  __shared__ float v_lds[K_PTS];
  __shared__ float red[8][K_PTS];
  const int tid = threadIdx.x;
  const int lane = tid & 63, wv = tid >> 6;
  const int b = blockIdx.x;
  v_lds[tid * 2 + 0] = 1.0f;
  v_lds[tid * 2 + 1] = 1.0f;
  __syncthreads();

  const int r0 = b * 64 + wv * 8;
  const uint4* Kb4 = (const uint4*)Kb;   // row stride = K_PTS/8 uint4

  for (int t = 0; t < ITERS; t++) {
    float vr[16];
#pragma unroll
    for (int q = 0; q < 4; q++) {
      float4 x = *(const float4*)&v_lds[lane * 16 + q * 4];
      vr[q*4+0] = x.x; vr[q*4+1] = x.y; vr[q*4+2] = x.z; vr[q*4+3] = x.w;
    }
    float ca[16] = {};
#pragma unroll
    for (int g = 0; g < 2; g++) {
      const int r = r0 + g * 4;
      uint4 w0[4], w1[4];
#pragma unroll
      for (int i = 0; i < 4; i++) {
        const uint4* rp = Kb4 + (size_t)(r + i) * (K_PTS / 8) + lane * 2;
        w0[i] = rp[0]; w1[i] = rp[1];
      }
      float f[4][16], s[4];
#pragma unroll
      for (int i = 0; i < 4; i++) {
        unpack2(w0[i].x, f[i][0], f[i][1]);   unpack2(w0[i].y, f[i][2], f[i][3]);
        unpack2(w0[i].z, f[i][4], f[i][5]);   unpack2(w0[i].w, f[i][6], f[i][7]);
        unpack2(w1[i].x, f[i][8], f[i][9]);   unpack2(w1[i].y, f[i][10], f[i][11]);
        unpack2(w1[i].z, f[i][12], f[i][13]); unpack2(w1[i].w, f[i][14], f[i][15]);
        float a = 0.f;
#pragma unroll
        for (int j = 0; j < 16; j++) a += f[i][j] * vr[j];
        s[i] = a;
      }
#pragma unroll
      for (int off = 32; off > 0; off >>= 1) {   // batched butterfly: 4 rows amortize the chain
        s[0] += __shfl_xor(s[0], off, 64);
        s[1] += __shfl_xor(s[1], off, 64);
        s[2] += __shfl_xor(s[2], off, 64);
        s[3] += __shfl_xor(s[3], off, 64);
      }
#pragma unroll
      for (int i = 0; i < 4; i++) {
        float ui = MU_F / (s[i] + 1e-8f);
        if (t == ITERS - 1 && lane == 0) u_out[r + i] = ui;
#pragma unroll
        for (int j = 0; j < 16; j++) ca[j] += ui * f[i][j];
      }
    }
    __syncthreads();
#pragma unroll
    for (int q = 0; q < 4; q++)
      *(float4*)&red[wv][lane * 16 + q * 4] =
          make_float4(ca[q*4+0], ca[q*4+1], ca[q*4+2], ca[q*4+3]);
    __syncthreads();
    {
      float s0 = 0.f, s1 = 0.f;
#pragma unroll
      for (int w8 = 0; w8 < 8; w8++) {
        float2 v2 = *(const float2*)&red[w8][tid * 2];
        s0 += v2.x; s1 += v2.y;
      }
      float* dst = accum + (size_t)(t + 1) * (NCOPY * K_PTS) + (size_t)(b & (NCOPY - 1)) * K_PTS + tid * 2;
      atomicAdd(dst + 0, s0);
      atomicAdd(dst + 1, s1);
    }
    __threadfence();
    __syncthreads();
    if (tid == 0) {
      __hip_atomic_fetch_add(&cnt[t], 1u, __ATOMIC_ACQ_REL, __HIP_MEMORY_SCOPE_AGENT);
      while (__hip_atomic_load(&cnt[t], __ATOMIC_ACQUIRE, __HIP_MEMORY_SCOPE_AGENT) < (unsigned)SINK_BLOCKS)
        __builtin_amdgcn_s_sleep(16);
    }
    __syncthreads();
    if (t + 1 < ITERS) {
      float* st = accum + (size_t)(t + 1) * (NCOPY * K_PTS);
      float s0 = 0.f, s1 = 0.f;
#pragma unroll
      for (int c = 0; c < NCOPY; c++) {   // agent-scope loads: bypass potentially-stale caches (G16)
        s0 += __hip_atomic_load(st + (size_t)c * K_PTS + tid * 2 + 0, __ATOMIC_RELAXED, __HIP_MEMORY_SCOPE_AGENT);
        s1 += __hip_atomic_load(st + (size_t)c * K_PTS + tid * 2 + 1, __ATOMIC_RELAXED, __HIP_MEMORY_SCOPE_AGENT);
      }
      v_lds[tid * 2 + 0] = NU_F / (s0 + 1e-8f);
      v_lds[tid * 2 + 1] = NU_F / (s1 + 1e-8f);
    }
    __syncthreads();
  }
}

// ---------------------------------------------------------------- final: T = u*k*v, loss = sum(T * (-eps*ln k))
__global__ __launch_bounds__(256) void final_kernel(const unsigned short* __restrict__ Kb,
                                                    const float* __restrict__ u,
                                                    const float* __restrict__ accum_last,
                                                    float* __restrict__ T,
                                                    float* __restrict__ loss) {
  __shared__ float v_lds[K_PTS];
  const int tid = threadIdx.x;
  {
    float4 s = make_float4(0.f, 0.f, 0.f, 0.f);
#pragma unroll
    for (int c = 0; c < NCOPY; c++) {
      float4 a = *(const float4*)&accum_last[c * K_PTS + tid * 4];
      s.x += a.x; s.y += a.y; s.z += a.z; s.w += a.w;
    }
    *(float4*)&v_lds[tid * 4] = make_float4(NU_F/(s.x+1e-8f), NU_F/(s.y+1e-8f),
                                            NU_F/(s.z+1e-8f), NU_F/(s.w+1e-8f));
  }
  __syncthreads();

  float lsum = 0.f;
  const unsigned int ngroups = (unsigned int)(N_PTS) * K_PTS / 8;
  for (unsigned int g = blockIdx.x * 256 + tid; g < ngroups; g += 2048u * 256u) {
    unsigned int e = g * 8;
    int row = (int)(e >> 10);
    int col = (int)(e & 1023);
    uint4 w = ((const uint4*)Kb)[g];
    float ui = u[row];
    float f[8];
    unpack2(w.x, f[0], f[1]); unpack2(w.y, f[2], f[3]);
    unpack2(w.z, f[4], f[5]); unpack2(w.w, f[6], f[7]);
    float4 v0 = *(const float4*)&v_lds[col];
    float4 v1 = *(const float4*)&v_lds[col + 4];
    float t[8];
    t[0]=ui*f[0]*v0.x; t[1]=ui*f[1]*v0.y; t[2]=ui*f[2]*v0.z; t[3]=ui*f[3]*v0.w;
    t[4]=ui*f[4]*v1.x; t[5]=ui*f[5]*v1.y; t[6]=ui*f[6]*v1.z; t[7]=ui*f[7]*v1.w;
    float4* Tp = (float4*)(T + e);
    Tp[0] = make_float4(t[0], t[1], t[2], t[3]);
    Tp[1] = make_float4(t[4], t[5], t[6], t[7]);
#pragma unroll
    for (int j = 0; j < 8; j++) lsum += t[j] * (-EPS_F * __logf(f[j]));
  }
  lsum = wave_reduce_sum(lsum);
  __shared__ float wsum[4];
  int lane = tid & 63, wv = tid >> 6;
  if (lane == 0) wsum[wv] = lsum;
  __syncthreads();
  if (tid == 0) atomicAdd(loss, wsum[0] + wsum[1] + wsum[2] + wsum[3]);
}

// ---------------------------------------------------------------- launcher
extern "C" void kernel_launch(void* const* d_in, const int* in_sizes, int n_in,
                              void* d_out, int out_size, void* d_ws, size_t ws_size,
                              hipStream_t stream) {
  const float* x = (const float*)d_in[0];
  const float* p = (const float*)d_in[1];
  float* T = (float*)d_out;
  float* loss = (float*)d_out + (size_t)N_PTS * K_PTS;
  __half* Ch = (__half*)d_out;  // fp16 C staged in d_out between gemm and expk

  unsigned short* Kb = (unsigned short*)d_ws;                 // 32 MB bf16 K_eps
  float* u = (float*)(Kb + (size_t)N_PTS * K_PTS);            // 16384
  float* dx = u + N_PTS;                                      // 16384
  float* pn = dx + N_PTS;                                     // 1024
  float* accum = pn + K_PTS;                                  // (ITERS+1)*NCOPY*1024
  unsigned int* cnt = (unsigned int*)(accum + (ITERS + 1) * NCOPY * K_PTS);  // 32
  unsigned int* maxbits = cnt + 32;

  init_kernel<<<((ITERS + 1) * NCOPY * K_PTS + 255) / 256, 256, 0, stream>>>(accum, cnt, maxbits, loss);
  rownorm_kernel<<<N_PTS / 4, 256, 0, stream>>>(x, dx, N_PTS);
  rownorm_kernel<<<K_PTS / 4, 256, 0, stream>>>(p, pn, K_PTS);
  gemm_kernel<<<dim3(K_PTS / 128, N_PTS / 128), 256, 0, stream>>>(x, p, dx, pn, Ch, maxbits);
  expk_kernel<<<(N_PTS * K_PTS) / (8 * 256), 256, 0, stream>>>(Ch, Kb, maxbits);

  sinkhorn_kernel<<<SINK_BLOCKS, 512, 0, stream>>>(Kb, accum, cnt, u);

  final_kernel<<<2048, 256, 0, stream>>>(Kb, u, accum + (size_t)ITERS * NCOPY * K_PTS, T, loss);
}

// Round 4
// 371.618 us; speedup vs baseline: 3.1285x; 3.1285x over previous
//
#include <hip/hip_runtime.h>
#include <hip/hip_fp16.h>
#include <cstddef>
#include <cstdint>

#define N_PTS 16384
#define K_PTS 1024
#define D_DIM 512
#define EPS_F 0.1f
#define ITERS 20
#define MU_F (1.0f/16384.0f)
#define NU_F (1.0f/1024.0f)
#define NCOPY 8
#define SINK_BLOCKS 256
#define FLAG_STRIDE 16   // 64B padding per flag: no false sharing
#define ACC_TOTAL ((ITERS + 1) * NCOPY * K_PTS)

typedef float f32x4 __attribute__((ext_vector_type(4)));
typedef short s16x8 __attribute__((ext_vector_type(8)));

__device__ __forceinline__ float wave_reduce_sum(float s) {
#pragma unroll
  for (int off = 32; off > 0; off >>= 1) s += __shfl_xor(s, off, 64);
  return s;
}
__device__ __forceinline__ float wave_reduce_max(float s) {
#pragma unroll
  for (int off = 32; off > 0; off >>= 1) s = fmaxf(s, __shfl_xor(s, off, 64));
  return s;
}
__device__ __forceinline__ unsigned short f2bf(float f) {  // RNE, finite inputs
  unsigned int b = __float_as_uint(f);
  b += 0x7fffu + ((b >> 16) & 1u);
  return (unsigned short)(b >> 16);
}
__device__ __forceinline__ float bf2f(unsigned short h) {
  return __uint_as_float(((unsigned int)h) << 16);
}

// ---------------------------------------------------------------- init
__global__ __launch_bounds__(256) void init_kernel(float* __restrict__ accum,
                                                   unsigned int* __restrict__ flags,
                                                   unsigned int* __restrict__ maxbits,
                                                   float* __restrict__ loss) {
  int i = blockIdx.x * 256 + threadIdx.x;
  if (i < ACC_TOTAL) accum[i] = 0.0f;
  if (i < SINK_BLOCKS * FLAG_STRIDE) flags[i] = 0u;
  if (i == 0) { *maxbits = 0u; *loss = 0.0f; }
}

// ---------------------------------------------------------------- row norms
__global__ __launch_bounds__(256) void rownorm_kernel(const float* __restrict__ A,
                                                      float* __restrict__ out, int rows) {
  int wave = (blockIdx.x * 256 + threadIdx.x) >> 6;
  int lane = threadIdx.x & 63;
  if (wave >= rows) return;
  const float4* rp = (const float4*)(A + (size_t)wave * D_DIM);
  float4 a = rp[lane];
  float4 b = rp[lane + 64];
  float s = a.x*a.x + a.y*a.y + a.z*a.z + a.w*a.w
          + b.x*b.x + b.y*b.y + b.z*b.z + b.w*b.w;
  s = wave_reduce_sum(s);
  if (lane == 0) out[wave] = s;
}

// ---------------------------------------------------------------- split-bf16 MFMA GEMM
// C(fp16, to d_out scratch) = dx + pn - 2*x@p^T, track global max (fp32 values).
#define LDSW 40  // 32 bf16 + 8 pad
__global__ __launch_bounds__(256) void gemm_kernel(const float* __restrict__ X,
                                                   const float* __restrict__ P,
                                                   const float* __restrict__ dx,
                                                   const float* __restrict__ pn,
                                                   __half* __restrict__ Ch,
                                                   unsigned int* __restrict__ maxbits) {
  __shared__ __align__(16) unsigned short Ah[128 * LDSW];
  __shared__ __align__(16) unsigned short Al[128 * LDSW];
  __shared__ __align__(16) unsigned short Bh[128 * LDSW];
  __shared__ __align__(16) unsigned short Bl[128 * LDSW];

  const int tid = threadIdx.x;
  const int lane = tid & 63, wv = tid >> 6;
  const int wm = wv >> 1, wn = wv & 1;
  const int m0 = blockIdx.y * 128, k0 = blockIdx.x * 128;
  const int lrow = tid >> 1, lhalf = tid & 1;

  const float* xrow = X + (size_t)(m0 + lrow) * D_DIM + lhalf * 16;
  const float* prow = P + (size_t)(k0 + lrow) * D_DIM + lhalf * 16;
  const int ldsoff = lrow * LDSW + lhalf * 16;

  f32x4 acc[4][4] = {};

  for (int d0 = 0; d0 < D_DIM; d0 += 32) {
    float av[16], bv[16];
    {
      const float4* xp = (const float4*)(xrow + d0);
      const float4* pp = (const float4*)(prow + d0);
#pragma unroll
      for (int q = 0; q < 4; q++) {
        float4 a = xp[q], b = pp[q];
        av[q*4+0]=a.x; av[q*4+1]=a.y; av[q*4+2]=a.z; av[q*4+3]=a.w;
        bv[q*4+0]=b.x; bv[q*4+1]=b.y; bv[q*4+2]=b.z; bv[q*4+3]=b.w;
      }
    }
    unsigned int ahu[8], alu[8], bhu[8], blu[8];
#pragma unroll
    for (int j = 0; j < 8; j++) {
      float f0 = av[2*j], f1 = av[2*j+1];
      unsigned short h0 = f2bf(f0), h1 = f2bf(f1);
      unsigned short l0 = f2bf(f0 - bf2f(h0)), l1 = f2bf(f1 - bf2f(h1));
      ahu[j] = (unsigned int)h0 | ((unsigned int)h1 << 16);
      alu[j] = (unsigned int)l0 | ((unsigned int)l1 << 16);
      f0 = bv[2*j]; f1 = bv[2*j+1];
      h0 = f2bf(f0); h1 = f2bf(f1);
      l0 = f2bf(f0 - bf2f(h0)); l1 = f2bf(f1 - bf2f(h1));
      bhu[j] = (unsigned int)h0 | ((unsigned int)h1 << 16);
      blu[j] = (unsigned int)l0 | ((unsigned int)l1 << 16);
    }
    __syncthreads();
    *(uint4*)&Ah[ldsoff]     = make_uint4(ahu[0], ahu[1], ahu[2], ahu[3]);
    *(uint4*)&Ah[ldsoff + 8] = make_uint4(ahu[4], ahu[5], ahu[6], ahu[7]);
    *(uint4*)&Al[ldsoff]     = make_uint4(alu[0], alu[1], alu[2], alu[3]);
    *(uint4*)&Al[ldsoff + 8] = make_uint4(alu[4], alu[5], alu[6], alu[7]);
    *(uint4*)&Bh[ldsoff]     = make_uint4(bhu[0], bhu[1], bhu[2], bhu[3]);
    *(uint4*)&Bh[ldsoff + 8] = make_uint4(bhu[4], bhu[5], bhu[6], bhu[7]);
    *(uint4*)&Bl[ldsoff]     = make_uint4(blu[0], blu[1], blu[2], blu[3]);
    *(uint4*)&Bl[ldsoff + 8] = make_uint4(blu[4], blu[5], blu[6], blu[7]);
    __syncthreads();

    const int offA = (wm * 64 + (lane & 15)) * LDSW + (lane >> 4) * 8;
    const int offB = (wn * 64 + (lane & 15)) * LDSW + (lane >> 4) * 8;
    s16x8 ah[4], al[4], bh[4], bl[4];
#pragma unroll
    for (int i = 0; i < 4; i++) {
      ah[i] = *(const s16x8*)&Ah[offA + i * 16 * LDSW];
      al[i] = *(const s16x8*)&Al[offA + i * 16 * LDSW];
      bh[i] = *(const s16x8*)&Bh[offB + i * 16 * LDSW];
      bl[i] = *(const s16x8*)&Bl[offB + i * 16 * LDSW];
    }
#pragma unroll
    for (int mi = 0; mi < 4; mi++)
#pragma unroll
      for (int ni = 0; ni < 4; ni++) {
        acc[mi][ni] = __builtin_amdgcn_mfma_f32_16x16x32_bf16(ah[mi], bh[ni], acc[mi][ni], 0, 0, 0);
        acc[mi][ni] = __builtin_amdgcn_mfma_f32_16x16x32_bf16(ah[mi], bl[ni], acc[mi][ni], 0, 0, 0);
        acc[mi][ni] = __builtin_amdgcn_mfma_f32_16x16x32_bf16(al[mi], bh[ni], acc[mi][ni], 0, 0, 0);
      }
  }

  // epilogue: C/D layout col=lane&15, row=(lane>>4)*4+reg
  float lmax = -3.4e38f;
#pragma unroll
  for (int mi = 0; mi < 4; mi++) {
    int rb = m0 + wm * 64 + mi * 16 + (lane >> 4) * 4;
    float dxv[4];
#pragma unroll
    for (int r = 0; r < 4; r++) dxv[r] = dx[rb + r];
#pragma unroll
    for (int ni = 0; ni < 4; ni++) {
      int c = k0 + wn * 64 + ni * 16 + (lane & 15);
      float pnc = pn[c];
#pragma unroll
      for (int r = 0; r < 4; r++) {
        float val = dxv[r] + pnc - 2.0f * acc[mi][ni][r];
        Ch[(size_t)(rb + r) * K_PTS + c] = __float2half(val);
        lmax = fmaxf(lmax, val);
      }
    }
  }
  lmax = wave_reduce_max(lmax);
  __shared__ float wmax[4];
  if (lane == 0) wmax[wv] = lmax;
  __syncthreads();
  if (tid == 0) {
    float m = fmaxf(fmaxf(wmax[0], wmax[1]), fmaxf(wmax[2], wmax[3]));
    atomicMax((int*)maxbits, __float_as_int(m));  // global max is positive
  }
}

// ---------------------------------------------------------------- persistent Sinkhorn, fully fused
// 256 blocks x 512 threads (1 block/CU). Wave wv of block b owns rows b*64+wv*8 .. +8;
// lane l owns cols [16l, 16l+16). K = exp(C*factor) built ONCE into 128 fp32 registers/lane.
// Per iter: dot rows with v (regs), batched butterfly reduce, u; K^T·u partials -> LDS ->
// 8-copy split atomics; contention-free flag barrier (per-block padded slot, parallel polls);
// v = NU/(colsum+1e-8) via agent-scope reads. After iter 20: T = u*k*v and loss from regs.
__global__ __launch_bounds__(512, 2) void sinkhorn_kernel(
    const __half* __restrict__ Ch,
    const unsigned int* __restrict__ maxbits,
    float* __restrict__ accum,          // (ITERS+1) stages x NCOPY x K_PTS
    unsigned int* __restrict__ flags,   // SINK_BLOCKS x FLAG_STRIDE
    float* __restrict__ T,
    float* __restrict__ loss) {
  __shared__ float v_lds[K_PTS];
  __shared__ float red[8][K_PTS];
  const int tid = threadIdx.x;
  const int lane = tid & 63, wv = tid >> 6;
  const int b = blockIdx.x;
  const int r0 = b * 64 + wv * 8;

  float factor;
  {
    float cmax = __int_as_float((int)*maxbits);
    factor = -1.0f / ((cmax + 1e-8f) * EPS_F);
  }
  // preamble: load 8 fp16 C rows, K in fp32 registers (128 VGPRs)
  float k[8][16];
#pragma unroll
  for (int i = 0; i < 8; i++) {
    const uint4* rp = (const uint4*)(Ch + (size_t)(r0 + i) * K_PTS + lane * 16);
    uint4 w0 = rp[0], w1 = rp[1];
    const __half2* h0 = (const __half2*)&w0;
    const __half2* h1 = (const __half2*)&w1;
#pragma unroll
    for (int q = 0; q < 4; q++) {
      float2 c2 = __half22float2(h0[q]);
      k[i][2*q+0] = __expf(c2.x * factor);
      k[i][2*q+1] = __expf(c2.y * factor);
      float2 d2 = __half22float2(h1[q]);
      k[i][8+2*q+0] = __expf(d2.x * factor);
      k[i][8+2*q+1] = __expf(d2.y * factor);
    }
  }
  v_lds[tid * 2 + 0] = 1.0f;
  v_lds[tid * 2 + 1] = 1.0f;
  __syncthreads();

  float ui[8];
  for (int t = 0; t < ITERS; t++) {
    float vr[16];
#pragma unroll
    for (int q = 0; q < 4; q++) {
      float4 x = *(const float4*)&v_lds[lane * 16 + q * 4];
      vr[q*4+0] = x.x; vr[q*4+1] = x.y; vr[q*4+2] = x.z; vr[q*4+3] = x.w;
    }
    float s[8];
#pragma unroll
    for (int i = 0; i < 8; i++) {
      float a = 0.f;
#pragma unroll
      for (int j = 0; j < 16; j++) a += k[i][j] * vr[j];
      s[i] = a;
    }
#pragma unroll
    for (int off = 32; off > 0; off >>= 1) {  // batched butterfly: 8 rows amortize the chain
#pragma unroll
      for (int i = 0; i < 8; i++) s[i] += __shfl_xor(s[i], off, 64);
    }
    float ca[16] = {};
#pragma unroll
    for (int i = 0; i < 8; i++) {
      ui[i] = MU_F / (s[i] + 1e-8f);
#pragma unroll
      for (int j = 0; j < 16; j++) ca[j] += ui[i] * k[i][j];
    }
    __syncthreads();  // guard red reuse from previous iteration
#pragma unroll
    for (int q = 0; q < 4; q++)
      *(float4*)&red[wv][lane * 16 + q * 4] =
          make_float4(ca[q*4+0], ca[q*4+1], ca[q*4+2], ca[q*4+3]);
    __syncthreads();
    {
      float s0 = 0.f, s1 = 0.f;
#pragma unroll
      for (int w8 = 0; w8 < 8; w8++) {
        float2 v2 = *(const float2*)&red[w8][tid * 2];
        s0 += v2.x; s1 += v2.y;
      }
      float* dst = accum + (size_t)(t + 1) * (NCOPY * K_PTS)
                 + (size_t)(b & (NCOPY - 1)) * K_PTS + tid * 2;
      atomicAdd(dst + 0, s0);
      atomicAdd(dst + 1, s1);
    }
    __syncthreads();  // all threads' atomics drained (vmcnt=0) before arrival
    if (tid == 0)
      __hip_atomic_store(&flags[(size_t)b * FLAG_STRIDE], (unsigned)(t + 1),
                         __ATOMIC_RELEASE, __HIP_MEMORY_SCOPE_AGENT);
    if (tid < SINK_BLOCKS) {
      while (__hip_atomic_load(&flags[(size_t)tid * FLAG_STRIDE],
                               __ATOMIC_RELAXED, __HIP_MEMORY_SCOPE_AGENT) < (unsigned)(t + 1))
        __builtin_amdgcn_s_sleep(4);
    }
    __syncthreads();
    {
      float* st = accum + (size_t)(t + 1) * (NCOPY * K_PTS);
      float s0 = 0.f, s1 = 0.f;
#pragma unroll
      for (int c = 0; c < NCOPY; c++) {  // agent-scope loads bypass stale caches (G16)
        s0 += __hip_atomic_load(st + (size_t)c * K_PTS + tid * 2 + 0,
                                __ATOMIC_RELAXED, __HIP_MEMORY_SCOPE_AGENT);
        s1 += __hip_atomic_load(st + (size_t)c * K_PTS + tid * 2 + 1,
                                __ATOMIC_RELAXED, __HIP_MEMORY_SCOPE_AGENT);
      }
      v_lds[tid * 2 + 0] = NU_F / (s0 + 1e-8f);
      v_lds[tid * 2 + 1] = NU_F / (s1 + 1e-8f);
    }
    __syncthreads();
  }

  // final: T = u*k*v (fp32 from registers), loss = sum(T * (-eps*ln k)).
  // Safe to clobber d_out's Ch region: every block's Ch reads finished before barrier 1.
  float lsum = 0.f;
#pragma unroll
  for (int i = 0; i < 8; i++) {
    float* Trow = T + (size_t)(r0 + i) * K_PTS + lane * 16;
#pragma unroll
    for (int q = 0; q < 4; q++) {
      float4 vv = *(const float4*)&v_lds[lane * 16 + q * 4];
      float4 tv;
      tv.x = ui[i] * k[i][q*4+0] * vv.x;
      tv.y = ui[i] * k[i][q*4+1] * vv.y;
      tv.z = ui[i] * k[i][q*4+2] * vv.z;
      tv.w = ui[i] * k[i][q*4+3] * vv.w;
      *(float4*)&Trow[q * 4] = tv;
      lsum += tv.x * (-EPS_F * __logf(k[i][q*4+0]));
      lsum += tv.y * (-EPS_F * __logf(k[i][q*4+1]));
      lsum += tv.z * (-EPS_F * __logf(k[i][q*4+2]));
      lsum += tv.w * (-EPS_F * __logf(k[i][q*4+3]));
    }
  }
  lsum = wave_reduce_sum(lsum);
  __shared__ float wsum[8];
  if (lane == 0) wsum[wv] = lsum;
  __syncthreads();
  if (tid == 0) {
    float m = 0.f;
#pragma unroll
    for (int i = 0; i < 8; i++) m += wsum[i];
    atomicAdd(loss, m);
  }
}

// ---------------------------------------------------------------- launcher
extern "C" void kernel_launch(void* const* d_in, const int* in_sizes, int n_in,
                              void* d_out, int out_size, void* d_ws, size_t ws_size,
                              hipStream_t stream) {
  const float* x = (const float*)d_in[0];
  const float* p = (const float*)d_in[1];
  float* T = (float*)d_out;
  float* loss = (float*)d_out + (size_t)N_PTS * K_PTS;
  __half* Ch = (__half*)d_out;  // fp16 C staged in d_out between gemm and sinkhorn

  float* accum = (float*)d_ws;                                   // ACC_TOTAL floats
  unsigned int* flags = (unsigned int*)(accum + ACC_TOTAL);      // 256*16 uints
  float* dx = (float*)(flags + SINK_BLOCKS * FLAG_STRIDE);       // 16384
  float* pn = dx + N_PTS;                                        // 1024
  unsigned int* maxbits = (unsigned int*)(pn + K_PTS);

  init_kernel<<<(ACC_TOTAL + SINK_BLOCKS * FLAG_STRIDE + 255) / 256, 256, 0, stream>>>(
      accum, flags, maxbits, loss);
  rownorm_kernel<<<N_PTS / 4, 256, 0, stream>>>(x, dx, N_PTS);
  rownorm_kernel<<<K_PTS / 4, 256, 0, stream>>>(p, pn, K_PTS);
  gemm_kernel<<<dim3(K_PTS / 128, N_PTS / 128), 256, 0, stream>>>(x, p, dx, pn, Ch, maxbits);
  sinkhorn_kernel<<<SINK_BLOCKS, 512, 0, stream>>>(Ch, maxbits, accum, flags, T, loss);
}

// Round 5
// 328.190 us; speedup vs baseline: 3.5425x; 1.1323x over previous
//
#include <hip/hip_runtime.h>
#include <hip/hip_fp16.h>
#include <cstddef>
#include <cstdint>

#define N_PTS 16384
#define K_PTS 1024
#define D_DIM 512
#define EPS_F 0.1f
#define ITERS 20
#define MU_F (1.0f/16384.0f)
#define NU_F (1.0f/1024.0f)
#define NCOPY 8
#define SINK_BLOCKS 256
#define FLAG_STRIDE 16   // 64B padding per flag
#define ACC_TOTAL ((ITERS + 1) * NCOPY * K_PTS)

typedef float f32x4 __attribute__((ext_vector_type(4)));
typedef short s16x8 __attribute__((ext_vector_type(8)));

__device__ __forceinline__ float wave_reduce_sum(float s) {
#pragma unroll
  for (int off = 32; off > 0; off >>= 1) s += __shfl_xor(s, off, 64);
  return s;
}
__device__ __forceinline__ float wave_reduce_max(float s) {
#pragma unroll
  for (int off = 32; off > 0; off >>= 1) s = fmaxf(s, __shfl_xor(s, off, 64));
  return s;
}

// ---------------------------------------------------------------- init
__global__ __launch_bounds__(256) void init_kernel(float* __restrict__ accum,
                                                   unsigned int* __restrict__ flags,
                                                   unsigned int* __restrict__ maxbits,
                                                   float* __restrict__ loss) {
  int i = blockIdx.x * 256 + threadIdx.x;
  if (i < ACC_TOTAL) accum[i] = 0.0f;
  if (i < SINK_BLOCKS * FLAG_STRIDE) flags[i] = 0u;
  if (i == 0) { *maxbits = 0u; *loss = 0.0f; }
}

// ---------------------------------------------------------------- split-bf16 MFMA GEMM
// C(fp16 -> d_out scratch) = |x|^2 + |p|^2 - 2*x@p^T; norms fused; global max tracked.
// LDS: XOR-swizzled granules (8 halfs), row stride 32 halfs, no padding.
__global__ __launch_bounds__(256) void gemm_kernel(const float* __restrict__ X,
                                                   const float* __restrict__ P,
                                                   __half* __restrict__ Ch,
                                                   unsigned int* __restrict__ maxbits) {
  __shared__ __align__(16) unsigned short Ah[128 * 32];
  __shared__ __align__(16) unsigned short Al[128 * 32];
  __shared__ __align__(16) unsigned short Bh[128 * 32];
  __shared__ __align__(16) unsigned short Bl[128 * 32];
  __shared__ float dxs[128];
  __shared__ float pns[128];

  const int tid = threadIdx.x;
  const int lane = tid & 63, wv = tid >> 6;
  const int wm = wv >> 1, wn = wv & 1;
  const int m0 = blockIdx.y * 128, k0 = blockIdx.x * 128;
  const int lrow = tid >> 1, lhalf = tid & 1;

  const float* xrow = X + (size_t)(m0 + lrow) * D_DIM + lhalf * 16;
  const float* prow = P + (size_t)(k0 + lrow) * D_DIM + lhalf * 16;
  const int sw = (lrow >> 1) & 3;                 // per-row granule swizzle
  const int woff0 = lrow * 32 + ((2 * lhalf + 0) ^ sw) * 8;
  const int woff1 = lrow * 32 + ((2 * lhalf + 1) ^ sw) * 8;

  f32x4 acc[4][4] = {};
  float sx = 0.f, sp = 0.f;

  for (int d0 = 0; d0 < D_DIM; d0 += 32) {
    float av[16], bv[16];
    {
      const float4* xp = (const float4*)(xrow + d0);
      const float4* pp = (const float4*)(prow + d0);
#pragma unroll
      for (int q = 0; q < 4; q++) {
        float4 a = xp[q], b = pp[q];
        av[q*4+0]=a.x; av[q*4+1]=a.y; av[q*4+2]=a.z; av[q*4+3]=a.w;
        bv[q*4+0]=b.x; bv[q*4+1]=b.y; bv[q*4+2]=b.z; bv[q*4+3]=b.w;
      }
    }
#pragma unroll
    for (int q = 0; q < 16; q++) { sx += av[q] * av[q]; sp += bv[q] * bv[q]; }
    // truncate-split: hi = trunc16(f), lo = bf16(f - hi); pack pairs via v_perm
    unsigned int ahu[8], alu[8], bhu[8], blu[8];
#pragma unroll
    for (int j = 0; j < 8; j++) {
      unsigned int a0 = __float_as_uint(av[2*j]), a1 = __float_as_uint(av[2*j+1]);
      ahu[j] = __builtin_amdgcn_perm(a1, a0, 0x07060302u);
      unsigned int l0 = __float_as_uint(av[2*j]   - __uint_as_float(a0 & 0xffff0000u));
      unsigned int l1 = __float_as_uint(av[2*j+1] - __uint_as_float(a1 & 0xffff0000u));
      alu[j] = __builtin_amdgcn_perm(l1, l0, 0x07060302u);
      unsigned int b0 = __float_as_uint(bv[2*j]), b1 = __float_as_uint(bv[2*j+1]);
      bhu[j] = __builtin_amdgcn_perm(b1, b0, 0x07060302u);
      unsigned int m0u = __float_as_uint(bv[2*j]   - __uint_as_float(b0 & 0xffff0000u));
      unsigned int m1u = __float_as_uint(bv[2*j+1] - __uint_as_float(b1 & 0xffff0000u));
      blu[j] = __builtin_amdgcn_perm(m1u, m0u, 0x07060302u);
    }
    __syncthreads();  // protect previous iteration's fragment reads
    *(uint4*)&Ah[woff0] = make_uint4(ahu[0], ahu[1], ahu[2], ahu[3]);
    *(uint4*)&Ah[woff1] = make_uint4(ahu[4], ahu[5], ahu[6], ahu[7]);
    *(uint4*)&Al[woff0] = make_uint4(alu[0], alu[1], alu[2], alu[3]);
    *(uint4*)&Al[woff1] = make_uint4(alu[4], alu[5], alu[6], alu[7]);
    *(uint4*)&Bh[woff0] = make_uint4(bhu[0], bhu[1], bhu[2], bhu[3]);
    *(uint4*)&Bh[woff1] = make_uint4(bhu[4], bhu[5], bhu[6], bhu[7]);
    *(uint4*)&Bl[woff0] = make_uint4(blu[0], blu[1], blu[2], blu[3]);
    *(uint4*)&Bl[woff1] = make_uint4(blu[4], blu[5], blu[6], blu[7]);
    __syncthreads();

    s16x8 ah[4], al[4], bh[4], bl[4];
#pragma unroll
    for (int i = 0; i < 4; i++) {
      int rA = wm * 64 + i * 16 + (lane & 15);
      int gA = (lane >> 4) ^ ((rA >> 1) & 3);
      ah[i] = *(const s16x8*)&Ah[rA * 32 + gA * 8];
      al[i] = *(const s16x8*)&Al[rA * 32 + gA * 8];
      int rB = wn * 64 + i * 16 + (lane & 15);
      int gB = (lane >> 4) ^ ((rB >> 1) & 3);
      bh[i] = *(const s16x8*)&Bh[rB * 32 + gB * 8];
      bl[i] = *(const s16x8*)&Bl[rB * 32 + gB * 8];
    }
#pragma unroll
    for (int mi = 0; mi < 4; mi++)
#pragma unroll
      for (int ni = 0; ni < 4; ni++) {
        acc[mi][ni] = __builtin_amdgcn_mfma_f32_16x16x32_bf16(ah[mi], bh[ni], acc[mi][ni], 0, 0, 0);
        acc[mi][ni] = __builtin_amdgcn_mfma_f32_16x16x32_bf16(ah[mi], bl[ni], acc[mi][ni], 0, 0, 0);
        acc[mi][ni] = __builtin_amdgcn_mfma_f32_16x16x32_bf16(al[mi], bh[ni], acc[mi][ni], 0, 0, 0);
      }
  }

  // publish fused norms (pair-halves combined via adjacent-lane shuffle)
  float px = sx + __shfl_xor(sx, 1, 64);
  float pp2 = sp + __shfl_xor(sp, 1, 64);
  __syncthreads();
  dxs[lrow] = px;
  pns[lrow] = pp2;
  __syncthreads();

  // epilogue: C/D layout col=lane&15, row=(lane>>4)*4+reg
  float lmax = -3.4e38f;
#pragma unroll
  for (int mi = 0; mi < 4; mi++) {
    int rloc = wm * 64 + mi * 16 + (lane >> 4) * 4;
    float dxv[4];
#pragma unroll
    for (int r = 0; r < 4; r++) dxv[r] = dxs[rloc + r];
#pragma unroll
    for (int ni = 0; ni < 4; ni++) {
      int cloc = wn * 64 + ni * 16 + (lane & 15);
      float pnc = pns[cloc];
#pragma unroll
      for (int r = 0; r < 4; r++) {
        float val = dxv[r] + pnc - 2.0f * acc[mi][ni][r];
        Ch[(size_t)(m0 + rloc + r) * K_PTS + k0 + cloc] = __float2half(val);
        lmax = fmaxf(lmax, val);
      }
    }
  }
  lmax = wave_reduce_max(lmax);
  __shared__ float wmax[4];
  if (lane == 0) wmax[wv] = lmax;
  __syncthreads();
  if (tid == 0) {
    float m = fmaxf(fmaxf(wmax[0], wmax[1]), fmaxf(wmax[2], wmax[3]));
    atomicMax((int*)maxbits, __float_as_int(m));  // global max is positive
  }
}

// ---------------------------------------------------------------- persistent Sinkhorn, fully fused
// 256 blocks x 512 threads. Wave wv owns rows r0..r0+8; lane owns cols {j*64+lane}.
// K = exp(C*factor) in 32 f32x4 registers/lane (no spill). Row sums via routed
// butterfly (10 DS ops) + readlane broadcast. Conflict-free LDS throughout.
__global__ __launch_bounds__(512, 2) void sinkhorn_kernel(
    const __half* __restrict__ Ch,
    const unsigned int* __restrict__ maxbits,
    float* __restrict__ accum,          // (ITERS+1) x NCOPY x K_PTS
    unsigned int* __restrict__ flags,   // SINK_BLOCKS x FLAG_STRIDE
    float* __restrict__ T,
    float* __restrict__ loss) {
  __shared__ float v_lds[K_PTS];
  __shared__ float red[8][K_PTS];
  const int tid = threadIdx.x;
  const int lane = tid & 63, wv = tid >> 6;
  const int b = blockIdx.x;
  const int r0 = b * 64 + wv * 8;

  float factor;
  {
    float cmax = __int_as_float((int)*maxbits);
    factor = -1.0f / ((cmax + 1e-8f) * EPS_F);
  }
  // preamble: K[row i][col (4q+e)*64+lane] -> k4[i*4+q][e]
  f32x4 k4[32];
#pragma unroll
  for (int i = 0; i < 8; i++) {
    const __half* rp = Ch + (size_t)(r0 + i) * K_PTS + lane;
#pragma unroll
    for (int q = 0; q < 4; q++) {
      f32x4 kk;
#pragma unroll
      for (int e = 0; e < 4; e++)
        kk[e] = __expf(__half2float(rp[(4 * q + e) * 64]) * factor);
      k4[i * 4 + q] = kk;
    }
  }
  v_lds[tid * 2 + 0] = 1.0f;
  v_lds[tid * 2 + 1] = 1.0f;
  __syncthreads();

  float su[8];
  for (int t = 0; t < ITERS; t++) {
    f32x4 vr4[4];
#pragma unroll
    for (int q = 0; q < 4; q++)
#pragma unroll
      for (int e = 0; e < 4; e++)
        vr4[q][e] = v_lds[(4 * q + e) * 64 + lane];

    float s[8];
#pragma unroll
    for (int i = 0; i < 8; i++) {
      f32x4 d = k4[i * 4 + 0] * vr4[0] + k4[i * 4 + 1] * vr4[1]
              + k4[i * 4 + 2] * vr4[2] + k4[i * 4 + 3] * vr4[3];
      s[i] = d[0] + d[1] + d[2] + d[3];
    }
    // routed reduce: steer row subsets by lane bits 5,4,3 (4+2+1 shuffles),
    // then xor4/2/1 completes the 64-lane sum. Row owned: (lane>>3)&7.
    {
      const bool h32 = (lane & 32) != 0;
      float a[4];
#pragma unroll
      for (int i = 0; i < 4; i++) {
        float x = h32 ? s[i] : s[i + 4];
        float y = h32 ? s[i + 4] : s[i];
        a[i] = y + __shfl_xor(x, 32, 64);
      }
      const bool h16 = (lane & 16) != 0;
      float c[2];
#pragma unroll
      for (int i = 0; i < 2; i++) {
        float x = h16 ? a[i] : a[i + 2];
        float y = h16 ? a[i + 2] : a[i];
        c[i] = y + __shfl_xor(x, 16, 64);
      }
      const bool h8 = (lane & 8) != 0;
      float x = h8 ? c[0] : c[1];
      float y = h8 ? c[1] : c[0];
      float w = y + __shfl_xor(x, 8, 64);
      w += __shfl_xor(w, 4, 64);
      w += __shfl_xor(w, 2, 64);
      w += __shfl_xor(w, 1, 64);
      float ui_local = MU_F / (w + 1e-8f);
#pragma unroll
      for (int i = 0; i < 8; i++)
        su[i] = __uint_as_float(__builtin_amdgcn_readlane(__float_as_uint(ui_local), i * 8));
    }
    f32x4 ca4[4] = {};
#pragma unroll
    for (int i = 0; i < 8; i++)
#pragma unroll
      for (int q = 0; q < 4; q++)
        ca4[q] += su[i] * k4[i * 4 + q];

    __syncthreads();  // red reuse guard
#pragma unroll
    for (int q = 0; q < 4; q++)
#pragma unroll
      for (int e = 0; e < 4; e++)
        red[wv][(4 * q + e) * 64 + lane] = ca4[q][e];
    __syncthreads();
    {
      float s0 = 0.f, s1 = 0.f;
#pragma unroll
      for (int w8 = 0; w8 < 8; w8++) {
        float2 v2 = *(const float2*)&red[w8][tid * 2];
        s0 += v2.x; s1 += v2.y;
      }
      float* dst = accum + (size_t)(t + 1) * (NCOPY * K_PTS)
                 + (size_t)(b & (NCOPY - 1)) * K_PTS + tid * 2;
      atomicAdd(dst + 0, s0);
      atomicAdd(dst + 1, s1);
    }
    __syncthreads();  // all block atomics drained before arrival
    if (tid == 0)
      __hip_atomic_store(&flags[(size_t)b * FLAG_STRIDE], (unsigned)(t + 1),
                         __ATOMIC_RELEASE, __HIP_MEMORY_SCOPE_AGENT);
    if (tid < SINK_BLOCKS) {
      while (__hip_atomic_load(&flags[(size_t)tid * FLAG_STRIDE],
                               __ATOMIC_RELAXED, __HIP_MEMORY_SCOPE_AGENT) < (unsigned)(t + 1))
        __builtin_amdgcn_s_sleep(4);
    }
    __syncthreads();
    {
      float* st = accum + (size_t)(t + 1) * (NCOPY * K_PTS);
      float s0 = 0.f, s1 = 0.f;
#pragma unroll
      for (int c = 0; c < NCOPY; c++) {  // agent-scope loads bypass stale caches (G16)
        s0 += __hip_atomic_load(st + (size_t)c * K_PTS + tid * 2 + 0,
                                __ATOMIC_RELAXED, __HIP_MEMORY_SCOPE_AGENT);
        s1 += __hip_atomic_load(st + (size_t)c * K_PTS + tid * 2 + 1,
                                __ATOMIC_RELAXED, __HIP_MEMORY_SCOPE_AGENT);
      }
      v_lds[tid * 2 + 0] = NU_F / (s0 + 1e-8f);
      v_lds[tid * 2 + 1] = NU_F / (s1 + 1e-8f);
    }
    __syncthreads();
  }

  // final: T = u*k*v from registers; loss = sum(T * (-eps*ln k)).
  // d_out clobber safe: all Ch reads happened before barrier 1.
  float lsum = 0.f;
#pragma unroll
  for (int i = 0; i < 8; i++) {
    float* Trow = T + (size_t)(r0 + i) * K_PTS + lane;
#pragma unroll
    for (int q = 0; q < 4; q++) {
#pragma unroll
      for (int e = 0; e < 4; e++) {
        int c = (4 * q + e) * 64;
        float kk = k4[i * 4 + q][e];
        float tv = su[i] * kk * v_lds[c + lane];
        Trow[c] = tv;
        lsum += tv * (-EPS_F * __logf(kk));
      }
    }
  }
  lsum = wave_reduce_sum(lsum);
  __shared__ float wsum[8];
  if (lane == 0) wsum[wv] = lsum;
  __syncthreads();
  if (tid == 0) {
    float m = 0.f;
#pragma unroll
    for (int i = 0; i < 8; i++) m += wsum[i];
    atomicAdd(loss, m);
  }
}

// ---------------------------------------------------------------- launcher
extern "C" void kernel_launch(void* const* d_in, const int* in_sizes, int n_in,
                              void* d_out, int out_size, void* d_ws, size_t ws_size,
                              hipStream_t stream) {
  const float* x = (const float*)d_in[0];
  const float* p = (const float*)d_in[1];
  float* T = (float*)d_out;
  float* loss = (float*)d_out + (size_t)N_PTS * K_PTS;
  __half* Ch = (__half*)d_out;  // fp16 C staged in d_out between gemm and sinkhorn

  float* accum = (float*)d_ws;                                   // ACC_TOTAL floats
  unsigned int* flags = (unsigned int*)(accum + ACC_TOTAL);      // 256*16
  unsigned int* maxbits = flags + SINK_BLOCKS * FLAG_STRIDE;

  init_kernel<<<(ACC_TOTAL + 255) / 256, 256, 0, stream>>>(accum, flags, maxbits, loss);
  gemm_kernel<<<dim3(K_PTS / 128, N_PTS / 128), 256, 0, stream>>>(x, p, Ch, maxbits);
  sinkhorn_kernel<<<SINK_BLOCKS, 512, 0, stream>>>(Ch, maxbits, accum, flags, T, loss);
}